// Round 1
// baseline (512.215 us; speedup 1.0000x reference)
//
#include <hip/hip_runtime.h>

#define THREADS 256
#define NWAVES (THREADS / 64)
#define CAP 2048

// One workgroup per row. Sparsemax support elements all satisfy x > max-1,
// so collect those few candidates, sort in LDS, compute tau exactly.
// Bisection fallback if a row has > CAP candidates (robustness only).
__global__ __launch_bounds__(THREADS) void sparsemax_kernel(
    const float* __restrict__ in, float* __restrict__ out, int V)
{
    const int row = blockIdx.x;
    const float* __restrict__ x = in + (size_t)row * V;
    float* __restrict__ y = out + (size_t)row * V;
    const int tid  = threadIdx.x;
    const int lane = tid & 63;
    const int wave = tid >> 6;

    __shared__ float s_red[NWAVES];
    __shared__ float s_cand[CAP];
    __shared__ float s_sorted[CAP];
    __shared__ int   s_count;
    __shared__ float s_m;
    __shared__ float s_tau;
    __shared__ float s_sum;

    const int V4 = V >> 2;
    const float4* __restrict__ x4 = reinterpret_cast<const float4*>(x);

    // ---- Phase A: row max ----
    float lmax = -3.4e38f;
    for (int i = tid; i < V4; i += THREADS) {
        float4 v = x4[i];
        lmax = fmaxf(fmaxf(lmax, v.x), fmaxf(v.y, fmaxf(v.z, v.w)));
    }
    for (int i = (V4 << 2) + tid; i < V; i += THREADS)
        lmax = fmaxf(lmax, x[i]);
    #pragma unroll
    for (int off = 32; off > 0; off >>= 1)
        lmax = fmaxf(lmax, __shfl_down(lmax, off, 64));
    if (lane == 0) s_red[wave] = lmax;
    __syncthreads();
    if (tid == 0) {
        float m = s_red[0];
        for (int w = 1; w < NWAVES; ++w) m = fmaxf(m, s_red[w]);
        s_m = m;
        s_count = 0;
    }
    __syncthreads();
    const float m = s_m;

    // ---- Phase B: collect candidates z = x - m in (-1, 0] ----
    for (int i = tid; i < V4; i += THREADS) {
        float4 v = x4[i];
        float a[4] = {v.x, v.y, v.z, v.w};
        #pragma unroll
        for (int j = 0; j < 4; ++j) {
            float z = a[j] - m;
            if (z > -1.0f) {
                int p = atomicAdd(&s_count, 1);
                if (p < CAP) s_cand[p] = z;
            }
        }
    }
    for (int i = (V4 << 2) + tid; i < V; i += THREADS) {
        float z = x[i] - m;
        if (z > -1.0f) {
            int p = atomicAdd(&s_count, 1);
            if (p < CAP) s_cand[p] = z;
        }
    }
    __syncthreads();
    const int n = s_count;

    if (n <= CAP) {
        // ---- Phase C: rank-sort descending (ties by buffer index) ----
        for (int i = tid; i < n; i += THREADS) {
            float zi = s_cand[i];
            int r = 0;
            for (int j = 0; j < n; ++j) {
                float zj = s_cand[j];
                r += (zj > zi) || (zj == zi && j < i);
            }
            s_sorted[r] = zi;
        }
        __syncthreads();
        if (tid == 0) {
            // k = count of j with 1 + j*z_j > cumsum_j  (prefix property)
            float cum = 0.0f;
            int k = 0;
            for (int j = 0; j < n; ++j) {
                cum += s_sorted[j];
                if (1.0f + (float)(j + 1) * s_sorted[j] > cum) k = j + 1;
            }
            float cumk = 0.0f;
            for (int j = 0; j < k; ++j) cumk += s_sorted[j];
            s_tau = (cumk - 1.0f) / (float)k;
        }
        __syncthreads();
    } else {
        // ---- Fallback: bisection on tau in [-1, 0] (never hit for N(0,1)) ----
        float lo = -1.0f, hi = 0.0f;
        for (int it = 0; it < 48; ++it) {
            float mid = 0.5f * (lo + hi);
            float ls = 0.0f;
            for (int i = tid; i < V4; i += THREADS) {
                float4 v = x4[i];
                ls += fmaxf(0.0f, v.x - m - mid);
                ls += fmaxf(0.0f, v.y - m - mid);
                ls += fmaxf(0.0f, v.z - m - mid);
                ls += fmaxf(0.0f, v.w - m - mid);
            }
            for (int i = (V4 << 2) + tid; i < V; i += THREADS)
                ls += fmaxf(0.0f, x[i] - m - mid);
            #pragma unroll
            for (int off = 32; off > 0; off >>= 1)
                ls += __shfl_down(ls, off, 64);
            if (lane == 0) s_red[wave] = ls;
            __syncthreads();
            if (tid == 0) {
                float s = 0.0f;
                for (int w = 0; w < NWAVES; ++w) s += s_red[w];
                s_sum = s;
            }
            __syncthreads();
            float s = s_sum;
            __syncthreads();
            if (s > 1.0f) lo = mid; else hi = mid;
        }
        if (tid == 0) s_tau = 0.5f * (lo + hi);
        __syncthreads();
    }

    const float tau = s_tau;
    const float thr = m + tau;

    // ---- Phase D: write output ----
    float4* __restrict__ y4 = reinterpret_cast<float4*>(y);
    for (int i = tid; i < V4; i += THREADS) {
        float4 v = x4[i];
        float4 o;
        o.x = fmaxf(0.0f, v.x - thr);
        o.y = fmaxf(0.0f, v.y - thr);
        o.z = fmaxf(0.0f, v.z - thr);
        o.w = fmaxf(0.0f, v.w - thr);
        y4[i] = o;
    }
    for (int i = (V4 << 2) + tid; i < V; i += THREADS)
        y[i] = fmaxf(0.0f, x[i] - thr);
}

extern "C" void kernel_launch(void* const* d_in, const int* in_sizes, int n_in,
                              void* d_out, int out_size, void* d_ws, size_t ws_size,
                              hipStream_t stream) {
    const float* in = (const float*)d_in[0];
    float* out = (float*)d_out;
    const int V = 32000;
    const int B = in_sizes[0] / V;
    sparsemax_kernel<<<B, THREADS, 0, stream>>>(in, out, V);
}

// Round 2
// 446.714 us; speedup vs baseline: 1.1466x; 1.1466x over previous
//
#include <hip/hip_runtime.h>

#define THREADS 1024
#define NWAVES (THREADS / 64)
#define K4 8          // float4 chunks per thread: 1024*8*4 = 32768 >= 32000
#define CAP 2048

// One workgroup per row; entire row held in registers (8 x float4 / thread).
// Sparsemax support elements satisfy x > max-1; collect those few candidates
// into LDS, rank-sort, compute tau exactly. Register-based bisection fallback.
__global__ __launch_bounds__(THREADS, 2) void sparsemax_kernel(
    const float* __restrict__ in, float* __restrict__ out, int V)
{
    const int row = blockIdx.x;
    const float* __restrict__ x = in + (size_t)row * V;
    float* __restrict__ y = out + (size_t)row * V;
    const int tid  = threadIdx.x;
    const int lane = tid & 63;
    const int wave = tid >> 6;

    __shared__ float s_red[NWAVES];
    __shared__ float s_cand[CAP];
    __shared__ float s_sorted[CAP];
    __shared__ int   s_count;
    __shared__ float s_m;
    __shared__ float s_tau;
    __shared__ float s_sum;

    const int V4 = V >> 2;   // 8000, V % 4 == 0
    const float4* __restrict__ x4 = reinterpret_cast<const float4*>(x);
    float4* __restrict__ y4 = reinterpret_cast<float4*>(y);

    // ---- Load entire row into registers (coalesced), compute local max ----
    float4 d[K4];
    float lmax = -3.4e38f;
    #pragma unroll
    for (int k = 0; k < K4; ++k) {
        int i = k * THREADS + tid;
        if (i < V4) {
            float4 v = x4[i];
            d[k] = v;
            lmax = fmaxf(fmaxf(lmax, v.x), fmaxf(v.y, fmaxf(v.z, v.w)));
        } else {
            d[k] = make_float4(-3.4e38f, -3.4e38f, -3.4e38f, -3.4e38f);
        }
    }

    // ---- Block max reduce ----
    #pragma unroll
    for (int off = 32; off > 0; off >>= 1)
        lmax = fmaxf(lmax, __shfl_down(lmax, off, 64));
    if (lane == 0) s_red[wave] = lmax;
    __syncthreads();
    if (tid == 0) {
        float m = s_red[0];
        for (int w = 1; w < NWAVES; ++w) m = fmaxf(m, s_red[w]);
        s_m = m;
        s_count = 0;
    }
    __syncthreads();
    const float m = s_m;

    // ---- Collect candidates z = x - m in (-1, 0] from registers ----
    #pragma unroll
    for (int k = 0; k < K4; ++k) {
        float a[4] = {d[k].x, d[k].y, d[k].z, d[k].w};
        #pragma unroll
        for (int j = 0; j < 4; ++j) {
            float z = a[j] - m;
            if (z > -1.0f) {
                int p = atomicAdd(&s_count, 1);
                if (p < CAP) s_cand[p] = z;
            }
        }
    }
    __syncthreads();
    const int n = s_count;

    if (n <= CAP) {
        // ---- Rank-sort descending (ties broken by buffer index) ----
        for (int i = tid; i < n; i += THREADS) {
            float zi = s_cand[i];
            int r = 0;
            for (int j = 0; j < n; ++j) {
                float zj = s_cand[j];
                r += (zj > zi) || (zj == zi && j < i);
            }
            s_sorted[r] = zi;
        }
        __syncthreads();
        if (tid == 0) {
            float cum = 0.0f;
            int k = 0;
            for (int j = 0; j < n; ++j) {
                cum += s_sorted[j];
                if (1.0f + (float)(j + 1) * s_sorted[j] > cum) k = j + 1;
            }
            float cumk = 0.0f;
            for (int j = 0; j < k; ++j) cumk += s_sorted[j];
            s_tau = (cumk - 1.0f) / (float)k;
        }
        __syncthreads();
    } else {
        // ---- Bisection fallback on tau in [-1, 0], from registers ----
        float lo = -1.0f, hi = 0.0f;
        for (int it = 0; it < 48; ++it) {
            float mid = 0.5f * (lo + hi);
            float ls = 0.0f;
            #pragma unroll
            for (int k = 0; k < K4; ++k) {
                ls += fmaxf(0.0f, d[k].x - m - mid);
                ls += fmaxf(0.0f, d[k].y - m - mid);
                ls += fmaxf(0.0f, d[k].z - m - mid);
                ls += fmaxf(0.0f, d[k].w - m - mid);
            }
            #pragma unroll
            for (int off = 32; off > 0; off >>= 1)
                ls += __shfl_down(ls, off, 64);
            if (lane == 0) s_red[wave] = ls;
            __syncthreads();
            if (tid == 0) {
                float s = 0.0f;
                for (int w = 0; w < NWAVES; ++w) s += s_red[w];
                s_sum = s;
            }
            __syncthreads();
            float s = s_sum;
            __syncthreads();
            if (s > 1.0f) lo = mid; else hi = mid;
        }
        if (tid == 0) s_tau = 0.5f * (lo + hi);
        __syncthreads();
    }

    const float thr = s_m + s_tau;

    // ---- Write output from registers ----
    #pragma unroll
    for (int k = 0; k < K4; ++k) {
        int i = k * THREADS + tid;
        if (i < V4) {
            float4 o;
            o.x = fmaxf(0.0f, d[k].x - thr);
            o.y = fmaxf(0.0f, d[k].y - thr);
            o.z = fmaxf(0.0f, d[k].z - thr);
            o.w = fmaxf(0.0f, d[k].w - thr);
            y4[i] = o;
        }
    }
}

extern "C" void kernel_launch(void* const* d_in, const int* in_sizes, int n_in,
                              void* d_out, int out_size, void* d_ws, size_t ws_size,
                              hipStream_t stream) {
    const float* in = (const float*)d_in[0];
    float* out = (float*)d_out;
    const int V = 32000;
    const int B = in_sizes[0] / V;
    sparsemax_kernel<<<B, THREADS, 0, stream>>>(in, out, V);
}